// Round 4
// baseline (297.460 us; speedup 1.0000x reference)
//
#include <hip/hip_runtime.h>
#include <math.h>

// Problem constants (from reference setup_inputs)
constexpr int Bn = 2, Cn = 256, Hn = 200, Wn = 304, Nroi = 1000;
constexpr int OH = 7, OW = 7, SRn = 2;
constexpr int NS = OH * SRn;   // 14 subsample rows/cols
constexpr int NP = NS * NS;    // 196 subsample positions per roi
constexpr int NBIN = OH * OW;  // 49
constexpr int HWn = Hn * Wn;   // 60800
constexpr float SCALE = 0.25f;

// ---------------------------------------------------------------------------
// Per-position sampling descriptor (matches JAX reference arithmetic, f32).
// ---------------------------------------------------------------------------
__device__ __forceinline__ void compute_desc(const float* __restrict__ r, int p,
                                             int& idx, int& dx, int& dyW,
                                             float4& w) {
  float cw = r[1] * SCALE - 0.5f;
  float ch = r[2] * SCALE - 0.5f;
  float rw = r[3] * SCALE;
  float rh = r[4] * SCALE;
  float theta = r[5] * 0.017453292519943295f;  // pi/180
  float cs = cosf(theta), sn = sinf(theta);
  float bin_h = rh * (1.0f / OH);
  float bin_w = rw * (1.0f / OW);
  int ki = p / NS;
  int kj = p - ki * NS;
  float ty = ((float)ki + 0.5f) * (1.0f / SRn);
  float tx = ((float)kj + 0.5f) * (1.0f / SRn);
  float yy = -0.5f * rh + ty * bin_h;
  float xx = -0.5f * rw + tx * bin_w;
  float y = yy * cs - xx * sn + ch;
  float x = yy * sn + xx * cs + cw;
  bool empty = (y < -1.0f) || (y > (float)Hn) || (x < -1.0f) || (x > (float)Wn);
  y = fmaxf(y, 0.0f);
  x = fmaxf(x, 0.0f);
  int yl = min(max((int)floorf(y), 0), Hn - 1);
  int xl = min(max((int)floorf(x), 0), Wn - 1);
  int yh = min(yl + 1, Hn - 1);
  int xh = min(xl + 1, Wn - 1);
  float ly = fminf(fmaxf(y - (float)yl, 0.0f), 1.0f);
  float lx = fminf(fmaxf(x - (float)xl, 0.0f), 1.0f);
  float hy = 1.0f - ly, hx = 1.0f - lx;
  if (empty) {
    w.x = w.y = w.z = w.w = 0.0f;
  } else {
    w.x = hy * hx;
    w.y = hy * lx;
    w.z = ly * hx;
    w.w = ly * lx;
  }
  idx = yl * Wn + xl;
  dx = xh - xl;
  dyW = (yh - yl) * Wn;
}

__device__ __forceinline__ unsigned bf16rne(float f) {
  unsigned u = __float_as_uint(f);
  return (u + 0x7fffu + ((u >> 16) & 1u)) >> 16;
}
__device__ __forceinline__ unsigned bf16pack(float lo, float hi) {
  return bf16rne(lo) | (bf16rne(hi) << 16);
}

// ---------------------------------------------------------------------------
// Kernel 0: spatial sort of roi indices (batch + Morton of 16px center tile).
// Single block, 512 threads, bitonic over 1024 packed u32 (key<<10 | idx).
// Morton adjacency is what creates within-block pixel reuse in roi_gather10.
// ---------------------------------------------------------------------------
__global__ __launch_bounds__(512) void sort_rois(const float* __restrict__ rois,
                                                 int* __restrict__ perm) {
  __shared__ unsigned a[1024];
  int t = threadIdx.x;
  for (int i = t; i < 1024; i += 512) {
    unsigned packed;
    if (i < Nroi) {
      const float* r = rois + (size_t)i * 6;
      int b = (int)r[0];
      int tx = min(max((int)(r[1] * SCALE * (1.0f / 16.0f)), 0), 31);
      int ty = min(max((int)(r[2] * SCALE * (1.0f / 16.0f)), 0), 31);
      unsigned m = 0;
#pragma unroll
      for (int bit = 0; bit < 5; ++bit) {
        m |= (((tx >> bit) & 1u) << (2 * bit)) | (((ty >> bit) & 1u) << (2 * bit + 1));
      }
      unsigned key = ((unsigned)b << 10) | m;  // 11 bits
      packed = (key << 10) | (unsigned)i;      // 21 bits total
    } else {
      packed = 0xFFFFFC00u | (unsigned)i;      // pad: sorts to the end
    }
    a[i] = packed;
  }
  for (int k = 2; k <= 1024; k <<= 1) {
    for (int j = k >> 1; j > 0; j >>= 1) {
      __syncthreads();
      int i = ((t & ~(j - 1)) << 1) | (t & (j - 1));
      bool up = ((i & k) == 0);
      unsigned x = a[i], y = a[i + j];
      if ((x > y) == up) {
        a[i] = y;
        a[i + j] = x;
      }
    }
  }
  __syncthreads();
  for (int i = t; i < Nroi; i += 512) perm[i] = (int)(a[i] & 1023u);
}

// ---------------------------------------------------------------------------
// Kernel 1 v3 (unchanged): transpose+downconvert feats (B,C,P) f32 -> (B,P,C) bf16.
// ---------------------------------------------------------------------------
constexpr int TPX = 64, TCH = 64, LP = TPX + 1;
__global__ __launch_bounds__(256) void transpose_bf16(const float* __restrict__ feats,
                                                      unsigned short* __restrict__ ft) {
  __shared__ float tile[TCH * LP];
  int p0 = blockIdx.x * TPX;
  int c0 = blockIdx.y * TCH;
  int b = blockIdx.z;
  int t = threadIdx.x;
  int px4 = t & 15, ch = t >> 4;
#pragma unroll
  for (int i = 0; i < 4; ++i) {
    int c = ch + 16 * i;
    const float4 v = *(const float4*)(feats + ((size_t)b * Cn + c0 + c) * HWn + p0 + px4 * 4);
    tile[c * LP + px4 * 4 + 0] = v.x;
    tile[c * LP + px4 * 4 + 1] = v.y;
    tile[c * LP + px4 * 4 + 2] = v.z;
    tile[c * LP + px4 * 4 + 3] = v.w;
  }
  __syncthreads();
  int o = t & 7;     // channel oct (8 ch = 16 B bf16)
  int px8 = t >> 3;  // 0..31
#pragma unroll
  for (int pass = 0; pass < 2; ++pass) {
    int p = px8 + 32 * pass;
    uint4 w4;
    w4.x = bf16pack(tile[(o * 8 + 0) * LP + p], tile[(o * 8 + 1) * LP + p]);
    w4.y = bf16pack(tile[(o * 8 + 2) * LP + p], tile[(o * 8 + 3) * LP + p]);
    w4.z = bf16pack(tile[(o * 8 + 4) * LP + p], tile[(o * 8 + 5) * LP + p]);
    w4.w = bf16pack(tile[(o * 8 + 6) * LP + p], tile[(o * 8 + 7) * LP + p]);
    *(uint4*)((char*)ft + (((size_t)b * HWn + p0 + p) * Cn + c0 + o * 8) * 2) = w4;
  }
}

// ---------------------------------------------------------------------------
// Kernel 2 v10: WITHIN-BLOCK pixel reuse (hardware-guaranteed L2 locality).
// Each block: 16 Morton-consecutive rois x 32-channel slice.
// Grid = 63 roi-groups x 8 slices = 504 blocks, 256 threads.
// Lane map per wave round (4 bins): cc=lane&3 (16-B chunk of the 64-B slice
// row), rq=(lane>>2)&3 -> (row,xcorner), b2=lane>>4 -> bin. s-loop of 4
// samples in registers, then shfl_xor(4,8) reduction over rq.
// Same wave-load count and logical bytes as v7; but rois j and j+1 overlap
// ~50-70% in touched lines -> repeats hit the block's OWN XCD L2/L1
// (no dispatch-mapping assumption) -> fabric bytes ~2x down.
// ---------------------------------------------------------------------------
constexpr int RPB = 16;                       // rois per block
constexpr int NG = (Nroi + RPB - 1) / RPB;    // 63 roi groups
__global__ __launch_bounds__(256, 4) void roi_gather10(const unsigned short* __restrict__ ft,
                                                       const float* __restrict__ rois,
                                                       const int* __restrict__ perm,
                                                       float* __restrict__ out) {
  __shared__ int4 s_m[NP];    // {idxB, dxB, dyB, 0} byte offsets into bf16 ft
  __shared__ float4 s_w[NP];
  __shared__ float s_out[32 * NBIN];  // 6272 B
  int cgrp = blockIdx.x & 7;   // channel slice 0..7 (32 ch each)
  int gidx = blockIdx.x >> 3;  // roi group 0..62
  int c0 = cgrp * 32;
  int t = threadIdx.x;
  int lane = t & 63;
  int wv = t >> 6;           // wave 0..3
  int cc = lane & 3;         // 16-B chunk (8 ch) within 64-B slice row
  int rq = (lane >> 2) & 3;  // row = rq>>1 (y_low/high), q = rq&1 (x_low/high)
  int b2 = lane >> 4;        // bin sub-index 0..3

  int roiEnd = min(Nroi - gidx * RPB, RPB);
  for (int j = 0; j < roiEnd; ++j) {
    int n = perm[gidx * RPB + j];
    const float* r = rois + (size_t)n * 6;
    if (t < NP) {
      int idx, dx, dy;
      float4 w;
      compute_desc(r, t, idx, dx, dy, w);
      s_m[t] = make_int4(idx * (Cn * 2), dx * (Cn * 2), dy * (Cn * 2), 0);
      s_w[t] = w;
    }
    __syncthreads();
    int b = (int)r[0];
    const char* base = (const char*)ft + ((size_t)b * HWn * Cn + c0 + cc * 8) * 2;

    for (int bin0 = wv * 4; bin0 < NBIN; bin0 += 16) {
      int bin = bin0 + b2;
      bool valid = bin < NBIN;
      int binc = valid ? bin : (NBIN - 1);  // invalid lanes alias bin 48's lines
      int bi = binc / OW;
      int bj = binc - bi * OW;
      int p00 = (bi * 2) * NS + bj * 2;
      float a0 = 0.f, a1 = 0.f, a2 = 0.f, a3 = 0.f;
      float a4 = 0.f, a5 = 0.f, a6 = 0.f, a7 = 0.f;
#pragma unroll
      for (int s = 0; s < 4; ++s) {
        int p = p00 + (s >> 1) * NS + (s & 1);
        int4 m = s_m[p];    // broadcast across the 16 lanes sharing b2
        float4 w = s_w[p];
        const char* A = base + m.x + ((rq & 1) ? m.y : 0) + ((rq & 2) ? m.z : 0);
        uint4 v = *(const uint4*)A;  // 8 ch bf16 of one corner pixel
        float wgt = (rq & 1) ? ((rq & 2) ? w.w : w.y) : ((rq & 2) ? w.z : w.x);
        if (!valid) wgt = 0.f;
        a0 += wgt * __uint_as_float(v.x << 16);
        a1 += wgt * __uint_as_float(v.x & 0xffff0000u);
        a2 += wgt * __uint_as_float(v.y << 16);
        a3 += wgt * __uint_as_float(v.y & 0xffff0000u);
        a4 += wgt * __uint_as_float(v.z << 16);
        a5 += wgt * __uint_as_float(v.z & 0xffff0000u);
        a6 += wgt * __uint_as_float(v.w << 16);
        a7 += wgt * __uint_as_float(v.w & 0xffff0000u);
      }
      // reduce over rq (lane bits 2,3): sum 4 corner contributions
#define RED(msk)                     \
      a0 += __shfl_xor(a0, msk);     \
      a1 += __shfl_xor(a1, msk);     \
      a2 += __shfl_xor(a2, msk);     \
      a3 += __shfl_xor(a3, msk);     \
      a4 += __shfl_xor(a4, msk);     \
      a5 += __shfl_xor(a5, msk);     \
      a6 += __shfl_xor(a6, msk);     \
      a7 += __shfl_xor(a7, msk);
      RED(4)
      RED(8)
#undef RED
      if (rq == 0 && valid) {
        s_out[(cc * 8 + 0) * NBIN + bin] = a0 * 0.25f;
        s_out[(cc * 8 + 1) * NBIN + bin] = a1 * 0.25f;
        s_out[(cc * 8 + 2) * NBIN + bin] = a2 * 0.25f;
        s_out[(cc * 8 + 3) * NBIN + bin] = a3 * 0.25f;
        s_out[(cc * 8 + 4) * NBIN + bin] = a4 * 0.25f;
        s_out[(cc * 8 + 5) * NBIN + bin] = a5 * 0.25f;
        s_out[(cc * 8 + 6) * NBIN + bin] = a6 * 0.25f;
        s_out[(cc * 8 + 7) * NBIN + bin] = a7 * 0.25f;
      }
    }
    __syncthreads();
    // Coalesced write: 32 ch x 49 bins = 1568 contiguous floats.
    float* og = out + ((size_t)n * Cn + c0) * NBIN;
    for (int i = t; i < 32 * NBIN; i += 256) og[i] = s_out[i];
    __syncthreads();
  }
}

// ---------------------------------------------------------------------------
// Fallback (if workspace too small): direct gather from (B,C,H,W), f32.
// ---------------------------------------------------------------------------
__global__ __launch_bounds__(256) void roi_direct(const float* __restrict__ feats,
                                                  const float* __restrict__ rois,
                                                  float* __restrict__ out) {
  __shared__ int s_idx[NP];
  __shared__ int s_dx[NP];
  __shared__ int s_dy[NP];
  __shared__ float4 s_w[NP];
  int n = blockIdx.x;
  const float* r = rois + (size_t)n * 6;
  int t = threadIdx.x;
  if (t < NP) {
    int idx, dx, dy;
    float4 w;
    compute_desc(r, t, idx, dx, dy, w);
    s_idx[t] = idx;
    s_dx[t] = dx;
    s_dy[t] = dy;
    s_w[t] = w;
  }
  __syncthreads();
  int b = (int)r[0];
  const float* f = feats + ((size_t)b * Cn + t) * HWn;
  float* o = out + ((size_t)n * Cn + t) * NBIN;
  for (int bi = 0; bi < OH; ++bi) {
    for (int bj = 0; bj < OW; ++bj) {
      float acc = 0.0f;
#pragma unroll
      for (int s = 0; s < 4; ++s) {
        int p = (bi * 2 + (s >> 1)) * NS + bj * 2 + (s & 1);
        int idx = s_idx[p];
        int dx = s_dx[p];
        int dy = s_dy[p];
        float4 w = s_w[p];
        acc += w.x * f[idx] + w.y * f[idx + dx] + w.z * f[idx + dy] + w.w * f[idx + dy + dx];
      }
      o[bi * OW + bj] = acc * 0.25f;
    }
  }
}

extern "C" void kernel_launch(void* const* d_in, const int* in_sizes, int n_in,
                              void* d_out, int out_size, void* d_ws, size_t ws_size,
                              hipStream_t stream) {
  const float* feats = (const float*)d_in[0];  // (2,256,200,304) f32
  const float* rois = (const float*)d_in[1];   // (1000,6) f32
  float* out = (float*)d_out;                  // (1000,256,7,7) f32

  size_t ftBytes = (size_t)Bn * HWn * Cn * sizeof(unsigned short);  // ~62.3 MB
  size_t need = ftBytes + 4096;
  if (ws_size >= need) {
    unsigned short* ft = (unsigned short*)d_ws;
    int* perm = (int*)((char*)d_ws + ftBytes);
    sort_rois<<<1, 512, 0, stream>>>(rois, perm);
    transpose_bf16<<<dim3(HWn / TPX, Cn / TCH, Bn), 256, 0, stream>>>(feats, ft);
    roi_gather10<<<dim3(NG * 8), 256, 0, stream>>>(ft, rois, perm, out);
  } else {
    roi_direct<<<Nroi, 256, 0, stream>>>(feats, rois, out);
  }
}

// Round 5
// 282.901 us; speedup vs baseline: 1.0515x; 1.0515x over previous
//
#include <hip/hip_runtime.h>
#include <math.h>

// Problem constants (from reference setup_inputs)
constexpr int Bn = 2, Cn = 256, Hn = 200, Wn = 304, Nroi = 1000;
constexpr int OH = 7, OW = 7, SRn = 2;
constexpr int NS = OH * SRn;   // 14 subsample rows/cols
constexpr int NP = NS * NS;    // 196 subsample positions per roi
constexpr int NBIN = OH * OW;  // 49
constexpr int HWn = Hn * Wn;   // 60800
constexpr float SCALE = 0.25f;

// ---------------------------------------------------------------------------
// Per-position sampling descriptor (matches JAX reference arithmetic, f32).
// ---------------------------------------------------------------------------
__device__ __forceinline__ void compute_desc(const float* __restrict__ r, int p,
                                             int& idx, int& dx, int& dyW,
                                             float4& w) {
  float cw = r[1] * SCALE - 0.5f;
  float ch = r[2] * SCALE - 0.5f;
  float rw = r[3] * SCALE;
  float rh = r[4] * SCALE;
  float theta = r[5] * 0.017453292519943295f;  // pi/180
  float cs = cosf(theta), sn = sinf(theta);
  float bin_h = rh * (1.0f / OH);
  float bin_w = rw * (1.0f / OW);
  int ki = p / NS;
  int kj = p - ki * NS;
  float ty = ((float)ki + 0.5f) * (1.0f / SRn);
  float tx = ((float)kj + 0.5f) * (1.0f / SRn);
  float yy = -0.5f * rh + ty * bin_h;
  float xx = -0.5f * rw + tx * bin_w;
  float y = yy * cs - xx * sn + ch;
  float x = yy * sn + xx * cs + cw;
  bool empty = (y < -1.0f) || (y > (float)Hn) || (x < -1.0f) || (x > (float)Wn);
  y = fmaxf(y, 0.0f);
  x = fmaxf(x, 0.0f);
  int yl = min(max((int)floorf(y), 0), Hn - 1);
  int xl = min(max((int)floorf(x), 0), Wn - 1);
  int yh = min(yl + 1, Hn - 1);
  int xh = min(xl + 1, Wn - 1);
  float ly = fminf(fmaxf(y - (float)yl, 0.0f), 1.0f);
  float lx = fminf(fmaxf(x - (float)xl, 0.0f), 1.0f);
  float hy = 1.0f - ly, hx = 1.0f - lx;
  if (empty) {
    w.x = w.y = w.z = w.w = 0.0f;
  } else {
    w.x = hy * hx;
    w.y = hy * lx;
    w.z = ly * hx;
    w.w = ly * lx;
  }
  idx = yl * Wn + xl;
  dx = xh - xl;
  dyW = (yh - yl) * Wn;
}

__device__ __forceinline__ unsigned bf16rne(float f) {
  unsigned u = __float_as_uint(f);
  return (u + 0x7fffu + ((u >> 16) & 1u)) >> 16;
}
__device__ __forceinline__ unsigned bf16pack(float lo, float hi) {
  return bf16rne(lo) | (bf16rne(hi) << 16);
}

// ---------------------------------------------------------------------------
// Kernel 0: spatial sort of roi indices (batch + Morton of 16px center tile).
// Single block, 512 threads, bitonic over 1024 packed u32 (key<<10 | idx).
// Morton adjacency creates the within-block pixel reuse in roi_gather11.
// ---------------------------------------------------------------------------
__global__ __launch_bounds__(512) void sort_rois(const float* __restrict__ rois,
                                                 int* __restrict__ perm) {
  __shared__ unsigned a[1024];
  int t = threadIdx.x;
  for (int i = t; i < 1024; i += 512) {
    unsigned packed;
    if (i < Nroi) {
      const float* r = rois + (size_t)i * 6;
      int b = (int)r[0];
      int tx = min(max((int)(r[1] * SCALE * (1.0f / 16.0f)), 0), 31);
      int ty = min(max((int)(r[2] * SCALE * (1.0f / 16.0f)), 0), 31);
      unsigned m = 0;
#pragma unroll
      for (int bit = 0; bit < 5; ++bit) {
        m |= (((tx >> bit) & 1u) << (2 * bit)) | (((ty >> bit) & 1u) << (2 * bit + 1));
      }
      unsigned key = ((unsigned)b << 10) | m;  // 11 bits
      packed = (key << 10) | (unsigned)i;      // 21 bits total
    } else {
      packed = 0xFFFFFC00u | (unsigned)i;      // pad: sorts to the end
    }
    a[i] = packed;
  }
  for (int k = 2; k <= 1024; k <<= 1) {
    for (int j = k >> 1; j > 0; j >>= 1) {
      __syncthreads();
      int i = ((t & ~(j - 1)) << 1) | (t & (j - 1));
      bool up = ((i & k) == 0);
      unsigned x = a[i], y = a[i + j];
      if ((x > y) == up) {
        a[i] = y;
        a[i + j] = x;
      }
    }
  }
  __syncthreads();
  for (int i = t; i < Nroi; i += 512) perm[i] = (int)(a[i] & 1023u);
}

// ---------------------------------------------------------------------------
// Kernel 1 v3 (unchanged): transpose+downconvert feats (B,C,P) f32 -> (B,P,C) bf16.
// ---------------------------------------------------------------------------
constexpr int TPX = 64, TCH = 64, LP = TPX + 1;
__global__ __launch_bounds__(256) void transpose_bf16(const float* __restrict__ feats,
                                                      unsigned short* __restrict__ ft) {
  __shared__ float tile[TCH * LP];
  int p0 = blockIdx.x * TPX;
  int c0 = blockIdx.y * TCH;
  int b = blockIdx.z;
  int t = threadIdx.x;
  int px4 = t & 15, ch = t >> 4;
#pragma unroll
  for (int i = 0; i < 4; ++i) {
    int c = ch + 16 * i;
    const float4 v = *(const float4*)(feats + ((size_t)b * Cn + c0 + c) * HWn + p0 + px4 * 4);
    tile[c * LP + px4 * 4 + 0] = v.x;
    tile[c * LP + px4 * 4 + 1] = v.y;
    tile[c * LP + px4 * 4 + 2] = v.z;
    tile[c * LP + px4 * 4 + 3] = v.w;
  }
  __syncthreads();
  int o = t & 7;     // channel oct (8 ch = 16 B bf16)
  int px8 = t >> 3;  // 0..31
#pragma unroll
  for (int pass = 0; pass < 2; ++pass) {
    int p = px8 + 32 * pass;
    uint4 w4;
    w4.x = bf16pack(tile[(o * 8 + 0) * LP + p], tile[(o * 8 + 1) * LP + p]);
    w4.y = bf16pack(tile[(o * 8 + 2) * LP + p], tile[(o * 8 + 3) * LP + p]);
    w4.z = bf16pack(tile[(o * 8 + 4) * LP + p], tile[(o * 8 + 5) * LP + p]);
    w4.w = bf16pack(tile[(o * 8 + 6) * LP + p], tile[(o * 8 + 7) * LP + p]);
    *(uint4*)((char*)ft + (((size_t)b * HWn + p0 + p) * Cn + c0 + o * 8) * 2) = w4;
  }
}

// ---------------------------------------------------------------------------
// Kernel 2 v11: v10's within-block reuse at v7's execution profile.
// Block = 8 Morton-consecutive rois x 32-channel slice.
// Grid = 125 groups x 8 slices = 1000 blocks x 4 waves, 4 blocks/CU
// (16 waves/CU, 2x v10's occupancy).
// Lane map: cc=lane&3 (16-B chunk of the 64-B slice row), q=(lane>>2)&1
// (x corner; x-pair is 128-B CONTIGUOUS in (B,P,C)), yb=(lane>>3)&1 (y
// corner), b2=lane>>4 (4 bins). One wave-load per subsample = 8 x 128-B
// segments (vs v10's 16 x 64-B). Corner combine: shfl_xor(4)+shfl_xor(8).
// Reuse across the 8 sequential rois hits the CU's own L2 (no dispatch-
// mapping assumption) -> keeps v10's FETCH ~204 MB at much higher TLP.
// ---------------------------------------------------------------------------
constexpr int RPB = 8;                 // rois per block
constexpr int NG = Nroi / RPB;         // 125 roi groups
__global__ __launch_bounds__(256, 4) void roi_gather11(const unsigned short* __restrict__ ft,
                                                       const float* __restrict__ rois,
                                                       const int* __restrict__ perm,
                                                       float* __restrict__ out) {
  __shared__ int4 s_m[NP];    // {idxB, dxB, dyB, 0} byte offsets into bf16 ft
  __shared__ float4 s_w[NP];
  __shared__ float s_out[32 * NBIN];  // 6272 B
  int slc = blockIdx.x & 7;    // channel slice 0..7 (32 ch each)
  int g = blockIdx.x >> 3;     // roi group 0..124
  int c0 = slc * 32;
  int t = threadIdx.x;
  int lane = t & 63;
  int wv = t >> 6;             // wave 0..3
  int cc = lane & 3;           // 16-B chunk (8 ch) within 64-B slice row
  int q = (lane >> 2) & 1;     // x corner
  int yb = (lane >> 3) & 1;    // y corner
  int b2 = lane >> 4;          // bin sub-index 0..3

#pragma unroll 1
  for (int j = 0; j < RPB; ++j) {
    int n = perm[g * RPB + j];
    const float* r = rois + (size_t)n * 6;
    if (t < NP) {
      int idx, dx, dy;
      float4 w;
      compute_desc(r, t, idx, dx, dy, w);
      s_m[t] = make_int4(idx * (Cn * 2), dx * (Cn * 2), dy * (Cn * 2), 0);
      s_w[t] = w;
    }
    __syncthreads();
    int b = (int)r[0];
    const char* base = (const char*)ft + ((size_t)b * HWn * Cn + c0 + cc * 8) * 2;

#pragma unroll
    for (int k = 0; k < 4; ++k) {
      int bin = k * 16 + wv * 4 + b2;
      bool valid = bin < NBIN;
      int binc = valid ? bin : (NBIN - 1);  // invalid lanes alias bin 48 (safe addr)
      int bi = binc / OW;
      int bj = binc - bi * OW;
      int p00 = (bi * 2) * NS + bj * 2;
      float a0 = 0.f, a1 = 0.f, a2 = 0.f, a3 = 0.f;
      float a4 = 0.f, a5 = 0.f, a6 = 0.f, a7 = 0.f;
#pragma unroll
      for (int s = 0; s < 4; ++s) {
        int p = p00 + (s >> 1) * NS + (s & 1);
        int4 m = s_m[p];    // 4 distinct addrs/wave (16-lane broadcast each)
        float4 w = s_w[p];
        const char* A = base + m.x + (q ? m.y : 0) + (yb ? m.z : 0);
        uint4 v = *(const uint4*)A;  // 8 ch bf16 of this lane's corner pixel
        float wgt = yb ? (q ? w.w : w.z) : (q ? w.y : w.x);
        if (!valid) wgt = 0.f;
        a0 += wgt * __uint_as_float(v.x << 16);
        a1 += wgt * __uint_as_float(v.x & 0xffff0000u);
        a2 += wgt * __uint_as_float(v.y << 16);
        a3 += wgt * __uint_as_float(v.y & 0xffff0000u);
        a4 += wgt * __uint_as_float(v.z << 16);
        a5 += wgt * __uint_as_float(v.z & 0xffff0000u);
        a6 += wgt * __uint_as_float(v.w << 16);
        a7 += wgt * __uint_as_float(v.w & 0xffff0000u);
      }
      // sum the 4 corners: x partner (xor 4), then y partner (xor 8)
#define RED(msk)                     \
      a0 += __shfl_xor(a0, msk);     \
      a1 += __shfl_xor(a1, msk);     \
      a2 += __shfl_xor(a2, msk);     \
      a3 += __shfl_xor(a3, msk);     \
      a4 += __shfl_xor(a4, msk);     \
      a5 += __shfl_xor(a5, msk);     \
      a6 += __shfl_xor(a6, msk);     \
      a7 += __shfl_xor(a7, msk);
      RED(4)
      RED(8)
#undef RED
      if (valid && q == 0 && yb == 0) {
        s_out[(cc * 8 + 0) * NBIN + bin] = a0 * 0.25f;
        s_out[(cc * 8 + 1) * NBIN + bin] = a1 * 0.25f;
        s_out[(cc * 8 + 2) * NBIN + bin] = a2 * 0.25f;
        s_out[(cc * 8 + 3) * NBIN + bin] = a3 * 0.25f;
        s_out[(cc * 8 + 4) * NBIN + bin] = a4 * 0.25f;
        s_out[(cc * 8 + 5) * NBIN + bin] = a5 * 0.25f;
        s_out[(cc * 8 + 6) * NBIN + bin] = a6 * 0.25f;
        s_out[(cc * 8 + 7) * NBIN + bin] = a7 * 0.25f;
      }
    }
    __syncthreads();
    // Coalesced write: 32 ch x 49 bins = 1568 contiguous floats.
    float* og = out + ((size_t)n * Cn + c0) * NBIN;
    for (int i = t; i < 32 * NBIN; i += 256) og[i] = s_out[i];
    __syncthreads();
  }
}

// ---------------------------------------------------------------------------
// Fallback (if workspace too small): direct gather from (B,C,H,W), f32.
// ---------------------------------------------------------------------------
__global__ __launch_bounds__(256) void roi_direct(const float* __restrict__ feats,
                                                  const float* __restrict__ rois,
                                                  float* __restrict__ out) {
  __shared__ int s_idx[NP];
  __shared__ int s_dx[NP];
  __shared__ int s_dy[NP];
  __shared__ float4 s_w[NP];
  int n = blockIdx.x;
  const float* r = rois + (size_t)n * 6;
  int t = threadIdx.x;
  if (t < NP) {
    int idx, dx, dy;
    float4 w;
    compute_desc(r, t, idx, dx, dy, w);
    s_idx[t] = idx;
    s_dx[t] = dx;
    s_dy[t] = dy;
    s_w[t] = w;
  }
  __syncthreads();
  int b = (int)r[0];
  const float* f = feats + ((size_t)b * Cn + t) * HWn;
  float* o = out + ((size_t)n * Cn + t) * NBIN;
  for (int bi = 0; bi < OH; ++bi) {
    for (int bj = 0; bj < OW; ++bj) {
      float acc = 0.0f;
#pragma unroll
      for (int s = 0; s < 4; ++s) {
        int p = (bi * 2 + (s >> 1)) * NS + bj * 2 + (s & 1);
        int idx = s_idx[p];
        int dx = s_dx[p];
        int dy = s_dy[p];
        float4 w = s_w[p];
        acc += w.x * f[idx] + w.y * f[idx + dx] + w.z * f[idx + dy] + w.w * f[idx + dy + dx];
      }
      o[bi * OW + bj] = acc * 0.25f;
    }
  }
}

extern "C" void kernel_launch(void* const* d_in, const int* in_sizes, int n_in,
                              void* d_out, int out_size, void* d_ws, size_t ws_size,
                              hipStream_t stream) {
  const float* feats = (const float*)d_in[0];  // (2,256,200,304) f32
  const float* rois = (const float*)d_in[1];   // (1000,6) f32
  float* out = (float*)d_out;                  // (1000,256,7,7) f32

  size_t ftBytes = (size_t)Bn * HWn * Cn * sizeof(unsigned short);  // ~62.3 MB
  size_t need = ftBytes + 4096;
  if (ws_size >= need) {
    unsigned short* ft = (unsigned short*)d_ws;
    int* perm = (int*)((char*)d_ws + ftBytes);
    sort_rois<<<1, 512, 0, stream>>>(rois, perm);
    transpose_bf16<<<dim3(HWn / TPX, Cn / TCH, Bn), 256, 0, stream>>>(feats, ft);
    roi_gather11<<<dim3(NG * 8), 256, 0, stream>>>(ft, rois, perm, out);
  } else {
    roi_direct<<<Nroi, 256, 0, stream>>>(feats, rois, out);
  }
}

// Round 6
// 241.945 us; speedup vs baseline: 1.2295x; 1.1693x over previous
//
#include <hip/hip_runtime.h>
#include <math.h>

// Problem constants (from reference setup_inputs)
constexpr int Bn = 2, Cn = 256, Hn = 200, Wn = 304, Nroi = 1000;
constexpr int OH = 7, OW = 7, SRn = 2;
constexpr int NS = OH * SRn;   // 14 subsample rows/cols
constexpr int NP = NS * NS;    // 196 subsample positions per roi
constexpr int NBIN = OH * OW;  // 49
constexpr int HWn = Hn * Wn;   // 60800
constexpr float SCALE = 0.25f;

// ---------------------------------------------------------------------------
// Per-position sampling descriptor (matches JAX reference arithmetic, f32).
// ---------------------------------------------------------------------------
__device__ __forceinline__ void compute_desc(const float* __restrict__ r, int p,
                                             int& idx, int& dx, int& dyW,
                                             float4& w) {
  float cw = r[1] * SCALE - 0.5f;
  float ch = r[2] * SCALE - 0.5f;
  float rw = r[3] * SCALE;
  float rh = r[4] * SCALE;
  float theta = r[5] * 0.017453292519943295f;  // pi/180
  float cs = cosf(theta), sn = sinf(theta);
  float bin_h = rh * (1.0f / OH);
  float bin_w = rw * (1.0f / OW);
  int ki = p / NS;
  int kj = p - ki * NS;
  float ty = ((float)ki + 0.5f) * (1.0f / SRn);
  float tx = ((float)kj + 0.5f) * (1.0f / SRn);
  float yy = -0.5f * rh + ty * bin_h;
  float xx = -0.5f * rw + tx * bin_w;
  float y = yy * cs - xx * sn + ch;
  float x = yy * sn + xx * cs + cw;
  bool empty = (y < -1.0f) || (y > (float)Hn) || (x < -1.0f) || (x > (float)Wn);
  y = fmaxf(y, 0.0f);
  x = fmaxf(x, 0.0f);
  int yl = min(max((int)floorf(y), 0), Hn - 1);
  int xl = min(max((int)floorf(x), 0), Wn - 1);
  int yh = min(yl + 1, Hn - 1);
  int xh = min(xl + 1, Wn - 1);
  float ly = fminf(fmaxf(y - (float)yl, 0.0f), 1.0f);
  float lx = fminf(fmaxf(x - (float)xl, 0.0f), 1.0f);
  float hy = 1.0f - ly, hx = 1.0f - lx;
  if (empty) {
    w.x = w.y = w.z = w.w = 0.0f;
  } else {
    w.x = hy * hx;
    w.y = hy * lx;
    w.z = ly * hx;
    w.w = ly * lx;
  }
  idx = yl * Wn + xl;
  dx = xh - xl;
  dyW = (yh - yl) * Wn;
}

__device__ __forceinline__ unsigned bf16rne(float f) {
  unsigned u = __float_as_uint(f);
  return (u + 0x7fffu + ((u >> 16) & 1u)) >> 16;
}
__device__ __forceinline__ unsigned bf16pack(float lo, float hi) {
  return bf16rne(lo) | (bf16rne(hi) << 16);
}

// ---------------------------------------------------------------------------
// Kernel 1 v3: transpose+downconvert feats (B,C,P) f32 -> ft (B,P,C) bf16.
// 64px x 64ch tiles; f32 staged in LDS; RNE convert on the write side.
// Read: 16B/lane coalesced. Write: 8 lanes x 16B = 128 B contiguous chunks,
// consecutive px at 512 B stride -> full 64 B lines covered.
// LDS banks both phases: {0,8,16,24}+small perm -> exactly 2-way = free.
// 186 MB total HBM traffic ≈ 30 µs — at the HBM roofline.
// ---------------------------------------------------------------------------
constexpr int TPX = 64, TCH = 64, LP = TPX + 1;
__global__ __launch_bounds__(256) void transpose_bf16(const float* __restrict__ feats,
                                                      unsigned short* __restrict__ ft) {
  __shared__ float tile[TCH * LP];
  int p0 = blockIdx.x * TPX;
  int c0 = blockIdx.y * TCH;
  int b = blockIdx.z;
  int t = threadIdx.x;
  int px4 = t & 15, ch = t >> 4;
#pragma unroll
  for (int i = 0; i < 4; ++i) {
    int c = ch + 16 * i;
    const float4 v = *(const float4*)(feats + ((size_t)b * Cn + c0 + c) * HWn + p0 + px4 * 4);
    tile[c * LP + px4 * 4 + 0] = v.x;
    tile[c * LP + px4 * 4 + 1] = v.y;
    tile[c * LP + px4 * 4 + 2] = v.z;
    tile[c * LP + px4 * 4 + 3] = v.w;
  }
  __syncthreads();
  int o = t & 7;     // channel oct (8 ch = 16 B bf16)
  int px8 = t >> 3;  // 0..31
#pragma unroll
  for (int pass = 0; pass < 2; ++pass) {
    int p = px8 + 32 * pass;
    uint4 w4;
    w4.x = bf16pack(tile[(o * 8 + 0) * LP + p], tile[(o * 8 + 1) * LP + p]);
    w4.y = bf16pack(tile[(o * 8 + 2) * LP + p], tile[(o * 8 + 3) * LP + p]);
    w4.z = bf16pack(tile[(o * 8 + 4) * LP + p], tile[(o * 8 + 5) * LP + p]);
    w4.w = bf16pack(tile[(o * 8 + 6) * LP + p], tile[(o * 8 + 7) * LP + p]);
    *(uint4*)((char*)ft + (((size_t)b * HWn + p0 + p) * Cn + c0 + o * 8) * 2) = w4;
  }
}

// ---------------------------------------------------------------------------
// Kernel 2 v6 (proven best, 241.8 µs total): gather from bf16 ft, f32 accum.
// block = (roi, channel-group of 64); lane map: o = lane&7 (8 consecutive
// channels, one uint4 = 16 B), g = lane>>3 (8 bins per wave-iteration).
// Per corner-read a wave covers 8 bins x 128 B contiguous chunks.
// Session evidence (v7-v11): fetch bytes, segment contiguity, Morton sort,
// XCD windowing, and occupancy tweaks are all neutral-or-worse vs this —
// the gather sits at the ~200 MB TCC-fetch / ~3.4 TB/s random-line fabric
// bound (L2 already captures ~50% of the 8x tap oversubscription).
// ---------------------------------------------------------------------------
__global__ __launch_bounds__(256, 2) void roi_gather6(const unsigned short* __restrict__ ft,
                                                      const float* __restrict__ rois,
                                                      float* __restrict__ out) {
  __shared__ int4 s_m[NP];   // {idxB, dxB, dyB, 0} byte offsets into bf16 ft
  __shared__ float4 s_w[NP];
  __shared__ __align__(16) float s_out[64 * NBIN];  // 3136 floats = 784 float4
  int n = blockIdx.x;
  int cg = blockIdx.y;  // channel group 0..3 (64 channels each)
  const float* r = rois + (size_t)n * 6;
  int t = threadIdx.x;
  if (t < NP) {
    int idx, dx, dy;
    float4 w;
    compute_desc(r, t, idx, dx, dy, w);
    s_m[t] = make_int4(idx * (Cn * 2), dx * (Cn * 2), dy * (Cn * 2), 0);
    s_w[t] = w;
  }
  __syncthreads();
  int b = (int)r[0];
  int lane = t & 63;
  int wv = t >> 6;
  int o = lane & 7;   // channel oct
  int g = lane >> 3;  // bin group 0..7
  const char* fb = (const char*)ft + ((size_t)b * HWn * Cn + cg * 64 + o * 8) * 2;

#pragma unroll
  for (int it = 0; it < 2; ++it) {
    int bin = it * 32 + wv * 8 + g;
    if (bin < NBIN) {
      int bi = bin / OW;
      int bj = bin - bi * OW;
      int p00 = (bi * 2) * NS + bj * 2;
      float acc0 = 0.f, acc1 = 0.f, acc2 = 0.f, acc3 = 0.f;
      float acc4 = 0.f, acc5 = 0.f, acc6 = 0.f, acc7 = 0.f;
#pragma unroll
      for (int s = 0; s < 4; ++s) {
        int p = p00 + (s >> 1) * NS + (s & 1);
        int4 m = s_m[p];     // broadcast within 8-lane groups
        float4 w = s_w[p];
        const char* A = fb + m.x;
        // 4 corner loads issued back-to-back (independent)
        uint4 v1 = *(const uint4*)(A);
        uint4 v2 = *(const uint4*)(A + m.y);
        uint4 v3 = *(const uint4*)(A + m.z);
        uint4 v4 = *(const uint4*)(A + m.z + m.y);
#define ACC(vv, ww)                                                        \
        acc0 += (ww) * __uint_as_float((vv).x << 16);                      \
        acc1 += (ww) * __uint_as_float((vv).x & 0xffff0000u);              \
        acc2 += (ww) * __uint_as_float((vv).y << 16);                      \
        acc3 += (ww) * __uint_as_float((vv).y & 0xffff0000u);              \
        acc4 += (ww) * __uint_as_float((vv).z << 16);                      \
        acc5 += (ww) * __uint_as_float((vv).z & 0xffff0000u);              \
        acc6 += (ww) * __uint_as_float((vv).w << 16);                      \
        acc7 += (ww) * __uint_as_float((vv).w & 0xffff0000u);
        ACC(v1, w.x)
        ACC(v2, w.y)
        ACC(v3, w.z)
        ACC(v4, w.w)
#undef ACC
      }
      s_out[(o * 8 + 0) * NBIN + bin] = acc0 * 0.25f;
      s_out[(o * 8 + 1) * NBIN + bin] = acc1 * 0.25f;
      s_out[(o * 8 + 2) * NBIN + bin] = acc2 * 0.25f;
      s_out[(o * 8 + 3) * NBIN + bin] = acc3 * 0.25f;
      s_out[(o * 8 + 4) * NBIN + bin] = acc4 * 0.25f;
      s_out[(o * 8 + 5) * NBIN + bin] = acc5 * 0.25f;
      s_out[(o * 8 + 6) * NBIN + bin] = acc6 * 0.25f;
      s_out[(o * 8 + 7) * NBIN + bin] = acc7 * 0.25f;
    }
  }
  __syncthreads();
  // Contiguous coalesced write-out: 64ch x 49bin = 3136 floats = 784 float4.
  const float4* s4 = (const float4*)s_out;
  float4* o4 = (float4*)(out + (size_t)n * Cn * NBIN + (size_t)cg * 64 * NBIN);
#pragma unroll
  for (int k = 0; k < 3; ++k) {
    o4[t + 256 * k] = s4[t + 256 * k];
  }
  if (t < 784 - 3 * 256) {
    o4[t + 256 * 3] = s4[t + 256 * 3];
  }
}

// ---------------------------------------------------------------------------
// Fallback (if workspace too small): direct gather from (B,C,H,W), f32.
// ---------------------------------------------------------------------------
__global__ __launch_bounds__(256) void roi_direct(const float* __restrict__ feats,
                                                  const float* __restrict__ rois,
                                                  float* __restrict__ out) {
  __shared__ int s_idx[NP];
  __shared__ int s_dx[NP];
  __shared__ int s_dy[NP];
  __shared__ float4 s_w[NP];
  int n = blockIdx.x;
  const float* r = rois + (size_t)n * 6;
  int t = threadIdx.x;
  if (t < NP) {
    int idx, dx, dy;
    float4 w;
    compute_desc(r, t, idx, dx, dy, w);
    s_idx[t] = idx;
    s_dx[t] = dx;
    s_dy[t] = dy;
    s_w[t] = w;
  }
  __syncthreads();
  int b = (int)r[0];
  const float* f = feats + ((size_t)b * Cn + t) * HWn;
  float* o = out + ((size_t)n * Cn + t) * NBIN;
  for (int bi = 0; bi < OH; ++bi) {
    for (int bj = 0; bj < OW; ++bj) {
      float acc = 0.0f;
#pragma unroll
      for (int s = 0; s < 4; ++s) {
        int p = (bi * 2 + (s >> 1)) * NS + bj * 2 + (s & 1);
        int idx = s_idx[p];
        int dx = s_dx[p];
        int dy = s_dy[p];
        float4 w = s_w[p];
        acc += w.x * f[idx] + w.y * f[idx + dx] + w.z * f[idx + dy] + w.w * f[idx + dy + dx];
      }
      o[bi * OW + bj] = acc * 0.25f;
    }
  }
}

extern "C" void kernel_launch(void* const* d_in, const int* in_sizes, int n_in,
                              void* d_out, int out_size, void* d_ws, size_t ws_size,
                              hipStream_t stream) {
  const float* feats = (const float*)d_in[0];  // (2,256,200,304) f32
  const float* rois = (const float*)d_in[1];   // (1000,6) f32
  float* out = (float*)d_out;                  // (1000,256,7,7) f32

  size_t need = (size_t)Bn * HWn * Cn * sizeof(unsigned short);  // ~62.3 MB
  if (ws_size >= need) {
    unsigned short* ft = (unsigned short*)d_ws;
    transpose_bf16<<<dim3(HWn / TPX, Cn / TCH, Bn), 256, 0, stream>>>(feats, ft);
    roi_gather6<<<dim3(Nroi, Cn / 64), 256, 0, stream>>>(ft, rois, out);
  } else {
    roi_direct<<<Nroi, 256, 0, stream>>>(feats, rois, out);
  }
}